// Round 12
// baseline (1390.487 us; speedup 1.0000x reference)
//
#include <hip/hip_runtime.h>
#include <hip/hip_bf16.h>
#include <math.h>

#define T_   64
#define B_   2048
#define OBS_ 48
#define H_   256
#define M1_  512
#define M2_  256
#define A_   12
#define BH_  (B_ * H_)
#define KP_  320   // padded K for scan: 64 (x, padded from 48) + 256 (h)
#define RPB_ 16    // rows per block
#define NBLK_ (B_ / RPB_)   // 128 blocks, no inter-block sync

typedef unsigned short u16;
typedef unsigned long long u64;
typedef __attribute__((ext_vector_type(8))) short bf16x8;
typedef __attribute__((ext_vector_type(4))) float f32x4;

static __device__ __forceinline__ u16 f2b(float f) {
    __hip_bfloat16 h = __float2bfloat16(f);
    return *reinterpret_cast<u16*>(&h);
}
static __device__ __forceinline__ float b2f(u16 u) {
    union { unsigned u32v; float f; } v; v.u32v = ((unsigned)u) << 16; return v.f;
}
static __device__ __forceinline__ float sigm(float x) {
    return 1.0f / (1.0f + __expf(-x));
}
static __device__ __forceinline__ float tanh_fast(float x) {
    x = fminf(fmaxf(x, -15.0f), 15.0f);
    float e = __expf(2.0f * x);
    return (e - 1.0f) / (e + 1.0f);
}
static __device__ __forceinline__ float elu(float x) {
    return x > 0.0f ? x : (__expf(x) - 1.0f);
}

// ---------------------------------------------------------------------------
// Unified pre-pass: blocks 0..4095 = xpad convert; 4096..5919 = weight prep.
// Wcat layout for lstm_solo (no slices - every block holds ALL weights):
//   out-row = ((w*2 + nf)*4 + g)*16 + jj   (w=wave 0..7, nf=col-half, g=gate)
//   <- src gate-row g*256 + (w*32 + nf*16 + jj)
//   K: 0..63 = x (padded) | 64..319 = h cols 0..255 (natural order)
// ---------------------------------------------------------------------------
__global__ void prep_all(const float* __restrict__ x, u16* __restrict__ xpad,
                         const float* __restrict__ W_ih, const float* __restrict__ W_hh,
                         const float* __restrict__ W1,  const float* __restrict__ W2,
                         const float* __restrict__ Wm,  const float* __restrict__ Ws,
                         u16* __restrict__ Wcat, u16* __restrict__ W1T,
                         u16* __restrict__ W2T,  u16* __restrict__ WhT) {
    const int blk = blockIdx.x, tid = threadIdx.x;
    if (blk < 4096) {
        const int gid = blk * 256 + tid;              // T*B*8 threads exactly
        const int r = gid >> 3, k0 = (gid & 7) * 8;
        u16 tmp[8];
        if (k0 < OBS_) {
            const float4 f0 = *(const float4*)(x + (size_t)r * OBS_ + k0);
            const float4 f1 = *(const float4*)(x + (size_t)r * OBS_ + k0 + 4);
            tmp[0] = f2b(f0.x); tmp[1] = f2b(f0.y); tmp[2] = f2b(f0.z); tmp[3] = f2b(f0.w);
            tmp[4] = f2b(f1.x); tmp[5] = f2b(f1.y); tmp[6] = f2b(f1.z); tmp[7] = f2b(f1.w);
        } else {
            #pragma unroll
            for (int i = 0; i < 8; ++i) tmp[i] = 0;
        }
        *(uint4*)(xpad + (size_t)gid * 8) = *(uint4*)tmp;
        return;
    }
    const int b = blk - 4096;                         // 0..1823
    if (b < 1024) {
        const int w = b >> 7, nf = (b >> 6) & 1, g = (b >> 4) & 3, jj = b & 15;
        const int src = g * 256 + w * 32 + nf * 16 + jj;
        for (int k = tid; k < KP_; k += 256) {
            float v;
            if (k < OBS_)    v = W_ih[src * OBS_ + k];
            else if (k < 64) v = 0.0f;
            else             v = W_hh[src * H_ + (k - 64)];
            Wcat[b * KP_ + k] = f2b(v);
        }
    } else if (b < 1536) {
        const int n = b - 1024;                       // W1T [512][256]
        W1T[n * 256 + tid] = f2b(W1[tid * M1_ + n]);
    } else if (b < 1792) {
        const int n = b - 1536;                       // W2T [256][512]
        W2T[n * 512 + tid]       = f2b(W2[tid * M2_ + n]);
        W2T[n * 512 + tid + 256] = f2b(W2[(tid + 256) * M2_ + n]);
    } else {
        const int n = b - 1792;                       // WhT [32][256]
        float v = 0.0f;
        if (n < 12)                 v = Wm[tid * A_ + n];
        else if (n >= 16 && n < 28) v = Ws[tid * A_ + (n - 16)];
        WhT[n * 256 + tid] = f2b(v);
    }
}

// ---------------------------------------------------------------------------
// Round-11 LSTM scan: ZERO inter-block communication.
//  - 128 blocks x 512 threads (8 waves), 16 batch rows each; every block
//    computes the FULL 1024 gate columns for its rows. The entire 640 KB
//    weight matrix is register/AGPR-resident across the block's 8 waves:
//    Bs[2][4][10] = 80 bf16x8 = 320 regs/lane + ~90 working < 450 no-spill.
//    (r6's spill was RUNTIME indexing; here every index is compile-time.)
//  - The 298-us round-7 scan spent ~90% of each 4.6-us step on the
//    pair-sync protocol (store-drain -> flag -> poll -> L3 partner fetch).
//    All of that is GONE: h feeds back through LDS only; hs stores are
//    fire-and-forget (the kernel boundary publishes them to the MLP).
//  - Per step: [issue x(t+1) loads] -> GEMM 80 MFMA/wave -> barrier ->
//    land x(t+1) -> epilogue (gates, cst, h->LDS masked, h->hs) -> barrier.
//  - Half the CUs idle: irrelevant - the scan is latency-bound, and the
//    MFMA floor per block-step is only 0.33 us.
// ---------------------------------------------------------------------------
#define ASM_(row, chunk) (a_sm + (size_t)(row) * 320 + (size_t)(((chunk) ^ ((row) & 7)) << 3))

__global__ __launch_bounds__(512, 1) void lstm_solo(
    const u16*  __restrict__ xpad,   // [T][B][64] bf16
    const int*  __restrict__ done,   // [T][B]
    const float* __restrict__ h0,    // [B][256] fp32
    const float* __restrict__ c0,    // [B][256] fp32
    u16*        __restrict__ hs,     // [T+1][B][256] bf16; slices 1..T written
    const u16*  __restrict__ Wcat,   // [1024 permuted][320] bf16
    const float* __restrict__ b_ih,
    const float* __restrict__ b_hh)
{
    __shared__ u16 a_sm[RPB_ * 320];   // 10 KB: chunks 0..7 = x, 8..39 = h

    const int tid  = threadIdx.x;
    const int lane = tid & 63;
    const int w    = tid >> 6;               // wave 0..7 -> h-cols [w*32, w*32+32)
    const int quad = lane >> 4, l16 = lane & 15;
    const int b0   = blockIdx.x * RPB_;

    // ---- fused biases for this lane's 2 col-halves x 4 gates ----
    float bsum[2][4];
    #pragma unroll
    for (int nf = 0; nf < 2; ++nf) {
        const int j = w * 32 + nf * 16 + l16;
        #pragma unroll
        for (int g = 0; g < 4; ++g) bsum[nf][g] = b_ih[g * 256 + j] + b_hh[g * 256 + j];
    }

    // ---- persistent c state (pre-masked with done[0]) ----
    float cst[2][4];
    #pragma unroll
    for (int r = 0; r < 4; ++r) {
        const int row = b0 + quad * 4 + r;
        const float kp = done[row] ? 0.0f : 1.0f;
        #pragma unroll
        for (int nf = 0; nf < 2; ++nf)
            cst[nf][r] = c0[(size_t)row * H_ + w * 32 + nf * 16 + l16] * kp;
    }

    // ---- FULL weight slice for this wave, register/AGPR-resident ----
    // 2 col-halves x 4 gates x 10 ktiles = 80 bf16x8 (320 regs). All
    // accesses below use compile-time indices (rule #20).
    bf16x8 Bs[2][4][10];
    #pragma unroll
    for (int nf = 0; nf < 2; ++nf)
        #pragma unroll
        for (int g = 0; g < 4; ++g) {
            const u16* wp = Wcat +
                (size_t)((((w * 2 + nf) * 4 + g) * 16) + l16) * KP_ + quad * 8;
            #pragma unroll
            for (int kt = 0; kt < 10; ++kt)
                Bs[nf][g][kt] = *(const bf16x8*)(wp + kt * 32);
        }

    // ---- pre-loop: stage x(0) (chunks 0..7) + h0 masked (chunks 8..39) ----
    if (tid < 128) {
        const int row = tid >> 3, seg = tid & 7;
        *(uint4*)ASM_(row, seg) =
            *(const uint4*)(xpad + (size_t)(b0 + row) * 64 + seg * 8);
    }
    {
        const int row = tid >> 5, c8 = tid & 31;
        const int dn = done[b0 + row];
        const float* hr = h0 + (size_t)(b0 + row) * H_ + c8 * 8;
        u16 tmp[8];
        #pragma unroll
        for (int e = 0; e < 8; ++e) tmp[e] = dn ? (u16)0 : f2b(hr[e]);
        *(uint4*)ASM_(row, 8 + c8) = *(uint4*)tmp;
    }
    __syncthreads();

    // ================= 64-step scan, zero inter-block sync =================
    for (int t = 0; t < T_; ++t) {
        // ---- T14: issue x(t+1) loads now; land them after the barrier ----
        uint4 xstage; int xrow = 0, xseg = 0;
        const bool do_x = (t + 1 < T_) && (tid < 128);
        if (do_x) {
            xrow = tid >> 3; xseg = tid & 7;
            xstage = *(const uint4*)(xpad +
                ((size_t)(t + 1) * B_ + b0 + xrow) * 64 + xseg * 8);
        }

        // ---- GEMM: 10 ds_read + 80 MFMA per wave; B entirely register ----
        f32x4 acc[2][4];
        #pragma unroll
        for (int nf = 0; nf < 2; ++nf)
            #pragma unroll
            for (int g = 0; g < 4; ++g) acc[nf][g] = (f32x4){0, 0, 0, 0};
        #pragma unroll
        for (int kt = 0; kt < 10; ++kt) {
            const bf16x8 af = *(const bf16x8*)ASM_(l16, kt * 4 + quad);
            #pragma unroll
            for (int nf = 0; nf < 2; ++nf)
                #pragma unroll
                for (int g = 0; g < 4; ++g)
                    acc[nf][g] = __builtin_amdgcn_mfma_f32_16x16x32_bf16(
                        af, Bs[nf][g][kt], acc[nf][g], 0, 0, 0);
        }
        __syncthreads();   // all waves done reading the A-tile

        // ---- land x(t+1) over x(t) (chunks 0..7, disjoint from h) ----
        if (do_x) *(uint4*)ASM_(xrow, xseg) = xstage;

        // ---- epilogue: gates -> c,h; h -> LDS (masked) + hs (unmasked) ----
        u16* hs1 = hs + (size_t)(t + 1) * BH_;
        #pragma unroll
        for (int r = 0; r < 4; ++r) {
            const int rowl = quad * 4 + r;
            const int rowg = b0 + rowl;
            const float kp = (t + 1 < T_)
                ? (done[(size_t)(t + 1) * B_ + rowg] ? 0.0f : 1.0f) : 1.0f;
            #pragma unroll
            for (int nf = 0; nf < 2; ++nf) {
                const int j = w * 32 + nf * 16 + l16;
                const float gi = acc[nf][0][r] + bsum[nf][0];
                const float gf = acc[nf][1][r] + bsum[nf][1];
                const float gg = acc[nf][2][r] + bsum[nf][2];
                const float go = acc[nf][3][r] + bsum[nf][3];
                const float cn = sigm(gf) * cst[nf][r] + sigm(gi) * tanh_fast(gg);
                const float h  = sigm(go) * tanh_fast(cn);
                cst[nf][r] = cn * kp;              // pre-mask c for step t+1
                *(ASM_(rowl, 8 + (j >> 3)) + (j & 7)) = f2b(h * kp);
                const unsigned hb = (unsigned)f2b(h);
                const unsigned ob = (unsigned)__shfl_xor((int)hb, 1);
                if ((l16 & 1) == 0) {              // pack (j, j+1) -> one u32 store
                    *(unsigned*)(hs1 + (size_t)rowg * H_ + (j & ~1)) = hb | (ob << 16);
                }
            }
        }
        __syncthreads();   // A-tile (x + h) ready for next step
    }
}

// ---------------------------------------------------------------------------
// MLP (round-7 proven, 211 us): 64 rows/block, 512 threads, two-phase y1,
// nontemporal u64 hs loads. Round-10's 4-phase variant REVERTED (+20 us:
// barrier count beat the occupancy gain, same as round 8).
// ---------------------------------------------------------------------------
#define SY(row, col) ((size_t)(row) * 256 + ((((col) >> 3) ^ ((row) & 7)) << 3) + ((col) & 7))

__global__ __launch_bounds__(512, 4) void mlp_mfma64(
    const u16*  __restrict__ hs,    // [nrows][256] bf16
    float*      __restrict__ out,   // [nrows][14]
    const float* __restrict__ lng, const float* __restrict__ lnb,
    const u16*  __restrict__ W1T, const float* __restrict__ b1,
    const u16*  __restrict__ W2T, const float* __restrict__ b2,
    const u16*  __restrict__ WhT,
    const float* __restrict__ bm, const float* __restrict__ bs)
{
    __shared__ u16 ybf[64 * 256];   // 32 KB swizzled: LN output, later y2
    __shared__ u16 yh [64 * 256];   // 32 KB swizzled: y1 column-half; later ls overlay

    const int tid  = threadIdx.x;
    const int lane = tid & 63;
    const int wave = tid >> 6;        // 0..7
    const int quad = lane >> 4, l16 = lane & 15;
    const int row0 = blockIdx.x * 64;

    // ---- LayerNorm: wave w -> rows w*8..w*8+7; lane holds 4 cols ----
    {
        const float4 gv = *(const float4*)(lng + lane * 4);
        const float4 bv = *(const float4*)(lnb + lane * 4);
        #pragma unroll
        for (int rr = 0; rr < 8; ++rr) {
            const int r = wave * 8 + rr;
            const u64 hv8 = __builtin_nontemporal_load(
                (const u64*)(hs + (size_t)(row0 + r) * H_ + lane * 4));
            const u16 h0v = (u16)(hv8 & 0xffff), h1v = (u16)((hv8 >> 16) & 0xffff);
            const u16 h2v = (u16)((hv8 >> 32) & 0xffff), h3v = (u16)(hv8 >> 48);
            const float v0 = b2f(h0v), v1 = b2f(h1v), v2 = b2f(h2v), v3 = b2f(h3v);
            float s  = v0 + v1 + v2 + v3;
            float ss = v0 * v0 + v1 * v1 + v2 * v2 + v3 * v3;
            #pragma unroll
            for (int off = 32; off > 0; off >>= 1) {
                s  += __shfl_down(s,  off);
                ss += __shfl_down(ss, off);
            }
            s = __shfl(s, 0); ss = __shfl(ss, 0);
            const float mu   = s * (1.0f / 256.0f);
            const float rstd = rsqrtf(ss * (1.0f / 256.0f) - mu * mu + 1e-5f);
            ushort4 o;
            o.x = f2b((v0 - mu) * rstd * gv.x + bv.x);
            o.y = f2b((v1 - mu) * rstd * gv.y + bv.y);
            o.z = f2b((v2 - mu) * rstd * gv.z + bv.z);
            o.w = f2b((v3 - mu) * rstd * gv.w + bv.w);
            *(ushort4*)(ybf + SY(r, lane * 4)) = o;
        }
    }
    __syncthreads();

    // ---- L2 partial accumulators: live across both phases ----
    f32x4 acc2[4][2];
    #pragma unroll
    for (int m = 0; m < 4; ++m)
        #pragma unroll
        for (int j = 0; j < 2; ++j) acc2[m][j] = (f32x4){0,0,0,0};

    #pragma unroll
    for (int ph = 0; ph < 2; ++ph) {
        // ---- L1 phase: y1 cols [ph*256, ph*256+256); wave n-slice 32 cols ----
        {
            f32x4 acc[4][2];
            #pragma unroll
            for (int m = 0; m < 4; ++m)
                #pragma unroll
                for (int j = 0; j < 2; ++j) acc[m][j] = (f32x4){0,0,0,0};
            const int n0 = ph * 256 + wave * 32;
            const u16* wp0 = W1T + (size_t)(n0 + l16) * 256 + quad * 8;
            const u16* wp1 = W1T + (size_t)(n0 + 16 + l16) * 256 + quad * 8;
            #pragma unroll
            for (int kt = 0; kt < 8; ++kt) {
                const int k0 = kt * 32;
                const bf16x8 bw0 = *(const bf16x8*)(wp0 + k0);
                const bf16x8 bw1 = *(const bf16x8*)(wp1 + k0);
                #pragma unroll
                for (int m = 0; m < 4; ++m) {
                    const bf16x8 af = *(const bf16x8*)(ybf + SY(m * 16 + l16, k0 + quad * 8));
                    acc[m][0] = __builtin_amdgcn_mfma_f32_16x16x32_bf16(af, bw0, acc[m][0], 0, 0, 0);
                    acc[m][1] = __builtin_amdgcn_mfma_f32_16x16x32_bf16(af, bw1, acc[m][1], 0, 0, 0);
                }
            }
            const float bb0 = b1[n0 + l16], bb1 = b1[n0 + 16 + l16];
            __syncthreads();   // yh free (prev phase consumed / first use)
            #pragma unroll
            for (int m = 0; m < 4; ++m)
                #pragma unroll
                for (int r = 0; r < 4; ++r) {
                    const int row = m * 16 + quad * 4 + r;
                    yh[SY(row, wave * 32 + l16)]      = f2b(elu(acc[m][0][r] + bb0));
                    yh[SY(row, wave * 32 + 16 + l16)] = f2b(elu(acc[m][1][r] + bb1));
                }
        }
        __syncthreads();

        // ---- L2 partial: K in [ph*256, ph*256+256); wave n-slice 32 cols ----
        {
            const int n0 = wave * 32;
            const u16* wp0 = W2T + (size_t)(n0 + l16) * 512 + ph * 256 + quad * 8;
            const u16* wp1 = W2T + (size_t)(n0 + 16 + l16) * 512 + ph * 256 + quad * 8;
            #pragma unroll
            for (int kt = 0; kt < 8; ++kt) {
                const int k0 = kt * 32;
                const bf16x8 bw0 = *(const bf16x8*)(wp0 + k0);
                const bf16x8 bw1 = *(const bf16x8*)(wp1 + k0);
                #pragma unroll
                for (int m = 0; m < 4; ++m) {
                    const bf16x8 af = *(const bf16x8*)(yh + SY(m * 16 + l16, k0 + quad * 8));
                    acc2[m][0] = __builtin_amdgcn_mfma_f32_16x16x32_bf16(af, bw0, acc2[m][0], 0, 0, 0);
                    acc2[m][1] = __builtin_amdgcn_mfma_f32_16x16x32_bf16(af, bw1, acc2[m][1], 0, 0, 0);
                }
            }
        }
        __syncthreads();
    }

    // ---- y2 = elu(acc2 + b2) -> ybf (LN data fully consumed) ----
    {
        const float bb0 = b2[wave * 32 + l16], bb1 = b2[wave * 32 + 16 + l16];
        #pragma unroll
        for (int m = 0; m < 4; ++m)
            #pragma unroll
            for (int r = 0; r < 4; ++r) {
                const int row = m * 16 + quad * 4 + r;
                ybf[SY(row, wave * 32 + l16)]      = f2b(elu(acc2[m][0][r] + bb0));
                ybf[SY(row, wave * 32 + 16 + l16)] = f2b(elu(acc2[m][1][r] + bb1));
            }
    }
    __syncthreads();

    // ---- Heads: waves 0..3 -> m-frag = wave; j=0 mean, j=1 logstd ----
    float* lsf = (float*)yh;   // overlay: [64][16] floats (yh free)
    if (wave < 4) {
        f32x4 a0 = {0,0,0,0}, a1 = {0,0,0,0};
        const u16* wp0 = WhT + (size_t)l16 * 256 + quad * 8;          // mean rows 0..15
        const u16* wp1 = WhT + (size_t)(16 + l16) * 256 + quad * 8;   // logstd rows 16..31
        #pragma unroll
        for (int kt = 0; kt < 8; ++kt) {
            const int k0 = kt * 32;
            const bf16x8 af  = *(const bf16x8*)(ybf + SY(wave * 16 + l16, k0 + quad * 8));
            const bf16x8 bw0 = *(const bf16x8*)(wp0 + k0);
            const bf16x8 bw1 = *(const bf16x8*)(wp1 + k0);
            a0 = __builtin_amdgcn_mfma_f32_16x16x32_bf16(af, bw0, a0, 0, 0, 0);
            a1 = __builtin_amdgcn_mfma_f32_16x16x32_bf16(af, bw1, a1, 0, 0, 0);
        }
        if (l16 < 12) {
            const float bbm = bm[l16], bbs = bs[l16];
            #pragma unroll
            for (int r = 0; r < 4; ++r) {
                const int row = wave * 16 + quad * 4 + r;
                out[(size_t)(row0 + row) * 14 + l16] = a0[r] + bbm;
                lsf[row * 16 + l16] = fminf(fmaxf(a1[r] + bbs, -5.0f), 2.0f);
            }
        }
    }
    __syncthreads();
    if (tid < 64) {
        float s = 0.0f;
        #pragma unroll
        for (int q = 0; q < 12; ++q) s += lsf[tid * 16 + q];
        const float LOG2PI = 1.8378770664093453f;
        out[(size_t)(row0 + tid) * 14 + 12] = -s - 6.0f * LOG2PI;
        out[(size_t)(row0 + tid) * 14 + 13] =  s + 6.0f + 6.0f * LOG2PI;
    }
}

// ---------------------------------------------------------------------------
extern "C" void kernel_launch(void* const* d_in, const int* in_sizes, int n_in,
                              void* d_out, int out_size, void* d_ws, size_t ws_size,
                              hipStream_t stream) {
    (void)in_sizes; (void)n_in; (void)out_size; (void)ws_size;
    const float* x    = (const float*)d_in[0];
    const int*   done = (const int*)  d_in[1];
    const float* h0   = (const float*)d_in[2];
    const float* c0   = (const float*)d_in[3];
    const float* W_ih = (const float*)d_in[4];
    const float* W_hh = (const float*)d_in[5];
    const float* b_ih = (const float*)d_in[6];
    const float* b_hh = (const float*)d_in[7];
    const float* lng  = (const float*)d_in[8];
    const float* lnb  = (const float*)d_in[9];
    const float* W1   = (const float*)d_in[10];
    const float* b1   = (const float*)d_in[11];
    const float* W2   = (const float*)d_in[12];
    const float* b2   = (const float*)d_in[13];
    const float* Wm   = (const float*)d_in[14];
    const float* bm   = (const float*)d_in[15];
    const float* Ws   = (const float*)d_in[16];
    const float* bs   = (const float*)d_in[17];
    float* out = (float*)d_out;

    // workspace carve (~52 MB; ws_size >= 135 MB confirmed)
    unsigned char* p = (unsigned char*)d_ws;
    u16* hs    = (u16*)p;              p += (size_t)(T_ + 1) * BH_ * 2;
    u16* xpad  = (u16*)p;              p += (size_t)T_ * B_ * 64 * 2;
    u16* Wcat  = (u16*)p;              p += (size_t)1024 * KP_ * 2;
    u16* W1T   = (u16*)p;              p += (size_t)M1_ * H_ * 2;
    u16* W2T   = (u16*)p;              p += (size_t)M2_ * M1_ * 2;
    u16* WhT   = (u16*)p;              p += (size_t)32 * H_ * 2;

    prep_all<<<4096 + 1824, 256, 0, stream>>>(x, xpad, W_ih, W_hh, W1, W2, Wm, Ws,
                                              Wcat, W1T, W2T, WhT);

    lstm_solo<<<NBLK_, 512, 0, stream>>>(
        xpad, done, h0, c0, hs, Wcat, b_ih, b_hh);

    mlp_mfma64<<<(T_ * B_) / 64, 512, 0, stream>>>(
        hs + BH_, out, lng, lnb, W1T, b1, W2T, b2, WhT, bm, bs);
}

// Round 13
// 1242.021 us; speedup vs baseline: 1.1195x; 1.1195x over previous
//
#include <hip/hip_runtime.h>
#include <hip/hip_bf16.h>
#include <math.h>

#define T_   64
#define B_   2048
#define OBS_ 48
#define H_   256
#define M1_  512
#define M2_  256
#define A_   12
#define BH_  (B_ * H_)
#define KP_  320   // padded K for scan: 64 (x, padded from 48) + 256 (h)
#define RPB_ 16    // rows per block
#define NBLK_ (B_ / RPB_)   // 128 blocks, ZERO inter-block sync

typedef unsigned short u16;
typedef unsigned long long u64;
typedef __attribute__((ext_vector_type(8))) short bf16x8;
typedef __attribute__((ext_vector_type(4))) float f32x4;

static __device__ __forceinline__ u16 f2b(float f) {
    __hip_bfloat16 h = __float2bfloat16(f);
    return *reinterpret_cast<u16*>(&h);
}
static __device__ __forceinline__ float b2f(u16 u) {
    union { unsigned u32v; float f; } v; v.u32v = ((unsigned)u) << 16; return v.f;
}
static __device__ __forceinline__ float sigm(float x) {
    return 1.0f / (1.0f + __expf(-x));
}
static __device__ __forceinline__ float tanh_fast(float x) {
    x = fminf(fmaxf(x, -15.0f), 15.0f);
    float e = __expf(2.0f * x);
    return (e - 1.0f) / (e + 1.0f);
}
static __device__ __forceinline__ float elu(float x) {
    return x > 0.0f ? x : (__expf(x) - 1.0f);
}

// ---------------------------------------------------------------------------
// Unified pre-pass: blocks 0..4095 = xpad convert; 4096..5919 = weight prep.
// Wcat layout for lstm_fuse (16 waves, each owns 16 h-cols, all 4 gates):
//   out-row = (w*4 + g)*16 + jj   (w = wave 0..15, g = gate, jj = col-in-16)
//   <- src gate-row g*256 + (w*16 + jj)
//   K natural: 0..63 = x (padded from 48) | 64..319 = h cols 0..255
// ---------------------------------------------------------------------------
__global__ void prep_all(const float* __restrict__ x, u16* __restrict__ xpad,
                         const float* __restrict__ W_ih, const float* __restrict__ W_hh,
                         const float* __restrict__ W1,  const float* __restrict__ W2,
                         const float* __restrict__ Wm,  const float* __restrict__ Ws,
                         u16* __restrict__ Wcat, u16* __restrict__ W1T,
                         u16* __restrict__ W2T,  u16* __restrict__ WhT) {
    const int blk = blockIdx.x, tid = threadIdx.x;
    if (blk < 4096) {
        const int gid = blk * 256 + tid;              // T*B*8 threads exactly
        const int r = gid >> 3, k0 = (gid & 7) * 8;
        u16 tmp[8];
        if (k0 < OBS_) {
            const float4 f0 = *(const float4*)(x + (size_t)r * OBS_ + k0);
            const float4 f1 = *(const float4*)(x + (size_t)r * OBS_ + k0 + 4);
            tmp[0] = f2b(f0.x); tmp[1] = f2b(f0.y); tmp[2] = f2b(f0.z); tmp[3] = f2b(f0.w);
            tmp[4] = f2b(f1.x); tmp[5] = f2b(f1.y); tmp[6] = f2b(f1.z); tmp[7] = f2b(f1.w);
        } else {
            #pragma unroll
            for (int i = 0; i < 8; ++i) tmp[i] = 0;
        }
        *(uint4*)(xpad + (size_t)gid * 8) = *(uint4*)tmp;
        return;
    }
    const int b = blk - 4096;                         // 0..1823
    if (b < 1024) {
        const int w = b >> 6, g = (b >> 4) & 3, jj = b & 15;
        const int src = g * 256 + w * 16 + jj;
        for (int k = tid; k < KP_; k += 256) {
            float v;
            if (k < OBS_)    v = W_ih[src * OBS_ + k];
            else if (k < 64) v = 0.0f;
            else             v = W_hh[src * H_ + (k - 64)];
            Wcat[b * KP_ + k] = f2b(v);
        }
    } else if (b < 1536) {
        const int n = b - 1024;                       // W1T [512][256]
        W1T[n * 256 + tid] = f2b(W1[tid * M1_ + n]);
    } else if (b < 1792) {
        const int n = b - 1536;                       // W2T [256][512]
        W2T[n * 512 + tid]       = f2b(W2[tid * M2_ + n]);
        W2T[n * 512 + tid + 256] = f2b(W2[(tid + 256) * M2_ + n]);
    } else {
        const int n = b - 1792;                       // WhT [32][256]
        float v = 0.0f;
        if (n < 12)                 v = Wm[tid * A_ + n];
        else if (n >= 16 && n < 28) v = Ws[tid * A_ + (n - 16)];
        WhT[n * 256 + tid] = f2b(v);
    }
}

// ---------------------------------------------------------------------------
// Round-13 LSTM scan: r7's pair FUSED into one 1024-thread block.
//  - 128 blocks x 1024 threads (16 waves), 16 batch rows each; wave w owns
//    h-cols [16w, 16w+16) with all 4 gates: Bs[4][10] = 160 regs/lane —
//    EXACTLY r7's proven per-wave weight size (AGPR-resident, no spill;
//    r12's 320/lane spilled, so this is the capacity-safe fusion).
//  - The entire r7 pair protocol (sc1 stores -> vmcnt drain -> flag ->
//    L3 poll -> 4 KB partner fetch, ~3 us of the 4.66 us step) collapses
//    into ONE __syncthreads(): h feeds back through the block's own LDS.
//    hs stores are fire-and-forget (kernel boundary publishes to the MLP).
//  - Per step: [issue x(t+1) loads] -> 40 MFMA/wave -> barrier ->
//    land x + epilogue (gates -> c,h; h -> LDS masked + hs) -> barrier.
//  - 128 of 256 CUs busy: fine - the scan is serial-latency-bound.
// ---------------------------------------------------------------------------
#define ASM_(row, chunk) (a_sm + (size_t)(row) * 320 + (size_t)(((chunk) ^ ((row) & 7)) << 3))

__global__ __launch_bounds__(1024, 1) void lstm_fuse(
    const u16*  __restrict__ xpad,   // [T][B][64] bf16
    const int*  __restrict__ done,   // [T][B]
    const float* __restrict__ h0,    // [B][256] fp32
    const float* __restrict__ c0,    // [B][256] fp32
    u16*        __restrict__ hs,     // [T+1][B][256] bf16; slices 1..T written
    const u16*  __restrict__ Wcat,   // [1024 permuted][320] bf16
    const float* __restrict__ b_ih,
    const float* __restrict__ b_hh)
{
    __shared__ u16 a_sm[RPB_ * 320];   // 10 KB: chunks 0..7 = x, 8..39 = h

    const int tid  = threadIdx.x;
    const int lane = tid & 63;
    const int w    = tid >> 6;               // wave 0..15 -> h-cols [w*16, w*16+16)
    const int quad = lane >> 4, l16 = lane & 15;
    const int b0   = blockIdx.x * RPB_;
    const int j    = w * 16 + l16;           // this lane's h column (0..255)

    // ---- fused biases: 4 gates of column j ----
    float bsum[4];
    #pragma unroll
    for (int g = 0; g < 4; ++g) bsum[g] = b_ih[g * 256 + j] + b_hh[g * 256 + j];

    // ---- persistent c state (pre-masked with done[0]) ----
    float cst[4];
    #pragma unroll
    for (int r = 0; r < 4; ++r) {
        const int row = b0 + quad * 4 + r;
        cst[r] = done[row] ? 0.0f : c0[(size_t)row * H_ + j];
    }

    // ---- this wave's weight slice: 4 gates x 10 kt = 160 regs (r7 size) ----
    // ALL accesses use compile-time indices (rule #20).
    bf16x8 Bs[4][10];
    #pragma unroll
    for (int g = 0; g < 4; ++g) {
        const u16* wp = Wcat + (size_t)((w * 4 + g) * 16 + l16) * KP_ + quad * 8;
        #pragma unroll
        for (int kt = 0; kt < 10; ++kt)
            Bs[g][kt] = *(const bf16x8*)(wp + kt * 32);
    }

    // ---- pre-loop: stage x(0) (chunks 0..7) + h0 masked (chunks 8..39) ----
    if (tid < 128) {
        const int row = tid >> 3, seg = tid & 7;
        *(uint4*)ASM_(row, seg) =
            *(const uint4*)(xpad + (size_t)(b0 + row) * 64 + seg * 8);
    }
    if (tid < 512) {
        const int row = tid >> 5, c8 = tid & 31;
        const int dn = done[b0 + row];
        const float* hr = h0 + (size_t)(b0 + row) * H_ + c8 * 8;
        u16 tmp[8];
        #pragma unroll
        for (int e = 0; e < 8; ++e) tmp[e] = dn ? (u16)0 : f2b(hr[e]);
        *(uint4*)ASM_(row, 8 + c8) = *(uint4*)tmp;
    }
    __syncthreads();

    // ================= 64-step scan, zero inter-block sync =================
    for (int t = 0; t < T_; ++t) {
        // ---- T14: issue x(t+1) loads now; land them after the barrier ----
        uint4 xstage; int xrow = 0, xseg = 0;
        const bool do_x = (t + 1 < T_) && (tid < 128);
        if (do_x) {
            xrow = tid >> 3; xseg = tid & 7;
            xstage = *(const uint4*)(xpad +
                ((size_t)(t + 1) * B_ + b0 + xrow) * 64 + xseg * 8);
        }

        // ---- GEMM: 10 ds_read + 40 MFMA per wave; B entirely register ----
        f32x4 acc[4];
        #pragma unroll
        for (int g = 0; g < 4; ++g) acc[g] = (f32x4){0, 0, 0, 0};
        #pragma unroll
        for (int kt = 0; kt < 10; ++kt) {
            const bf16x8 af = *(const bf16x8*)ASM_(l16, kt * 4 + quad);
            #pragma unroll
            for (int g = 0; g < 4; ++g)
                acc[g] = __builtin_amdgcn_mfma_f32_16x16x32_bf16(af, Bs[g][kt], acc[g], 0, 0, 0);
        }
        __syncthreads();   // all waves done reading the A-tile

        // ---- land x(t+1) over x(t) (chunks 0..7, disjoint from h) ----
        if (do_x) *(uint4*)ASM_(xrow, xseg) = xstage;

        // ---- epilogue: gates -> c,h; h -> LDS (masked) + hs (unmasked) ----
        u16* hs1 = hs + (size_t)(t + 1) * BH_;
        #pragma unroll
        for (int r = 0; r < 4; ++r) {
            const int rowl = quad * 4 + r;
            const int rowg = b0 + rowl;
            const float gi = acc[0][r] + bsum[0];
            const float gf = acc[1][r] + bsum[1];
            const float gg = acc[2][r] + bsum[2];
            const float go = acc[3][r] + bsum[3];
            const float cn = sigm(gf) * cst[r] + sigm(gi) * tanh_fast(gg);
            const float h  = sigm(go) * tanh_fast(cn);
            const float kp = (t + 1 < T_)
                ? (done[(size_t)(t + 1) * B_ + rowg] ? 0.0f : 1.0f) : 1.0f;
            cst[r] = cn * kp;                      // pre-mask c for step t+1
            *(ASM_(rowl, 8 + (j >> 3)) + (j & 7)) = f2b(h * kp);
            const unsigned hb = (unsigned)f2b(h);  // unmasked history to global
            const unsigned ob = (unsigned)__shfl_xor((int)hb, 1);
            if ((l16 & 1) == 0) {                  // pack (j, j+1) -> one u32 store
                *(unsigned*)(hs1 + (size_t)rowg * H_ + (j & ~1)) = hb | (ob << 16);
            }
        }
        __syncthreads();   // A-tile (x + h) ready for next step
    }
}

// ---------------------------------------------------------------------------
// MLP (round-7 proven, 211 us): 64 rows/block, 512 threads, two-phase y1,
// nontemporal u64 hs loads. (r8 32-row and r10 4-phase variants both
// regressed; this is the best measured MLP.)
// ---------------------------------------------------------------------------
#define SY(row, col) ((size_t)(row) * 256 + ((((col) >> 3) ^ ((row) & 7)) << 3) + ((col) & 7))

__global__ __launch_bounds__(512, 4) void mlp_mfma64(
    const u16*  __restrict__ hs,    // [nrows][256] bf16
    float*      __restrict__ out,   // [nrows][14]
    const float* __restrict__ lng, const float* __restrict__ lnb,
    const u16*  __restrict__ W1T, const float* __restrict__ b1,
    const u16*  __restrict__ W2T, const float* __restrict__ b2,
    const u16*  __restrict__ WhT,
    const float* __restrict__ bm, const float* __restrict__ bs)
{
    __shared__ u16 ybf[64 * 256];   // 32 KB swizzled: LN output, later y2
    __shared__ u16 yh [64 * 256];   // 32 KB swizzled: y1 column-half; later ls overlay

    const int tid  = threadIdx.x;
    const int lane = tid & 63;
    const int wave = tid >> 6;        // 0..7
    const int quad = lane >> 4, l16 = lane & 15;
    const int row0 = blockIdx.x * 64;

    // ---- LayerNorm: wave w -> rows w*8..w*8+7; lane holds 4 cols ----
    {
        const float4 gv = *(const float4*)(lng + lane * 4);
        const float4 bv = *(const float4*)(lnb + lane * 4);
        #pragma unroll
        for (int rr = 0; rr < 8; ++rr) {
            const int r = wave * 8 + rr;
            const u64 hv8 = __builtin_nontemporal_load(
                (const u64*)(hs + (size_t)(row0 + r) * H_ + lane * 4));
            const u16 h0v = (u16)(hv8 & 0xffff), h1v = (u16)((hv8 >> 16) & 0xffff);
            const u16 h2v = (u16)((hv8 >> 32) & 0xffff), h3v = (u16)(hv8 >> 48);
            const float v0 = b2f(h0v), v1 = b2f(h1v), v2 = b2f(h2v), v3 = b2f(h3v);
            float s  = v0 + v1 + v2 + v3;
            float ss = v0 * v0 + v1 * v1 + v2 * v2 + v3 * v3;
            #pragma unroll
            for (int off = 32; off > 0; off >>= 1) {
                s  += __shfl_down(s,  off);
                ss += __shfl_down(ss, off);
            }
            s = __shfl(s, 0); ss = __shfl(ss, 0);
            const float mu   = s * (1.0f / 256.0f);
            const float rstd = rsqrtf(ss * (1.0f / 256.0f) - mu * mu + 1e-5f);
            ushort4 o;
            o.x = f2b((v0 - mu) * rstd * gv.x + bv.x);
            o.y = f2b((v1 - mu) * rstd * gv.y + bv.y);
            o.z = f2b((v2 - mu) * rstd * gv.z + bv.z);
            o.w = f2b((v3 - mu) * rstd * gv.w + bv.w);
            *(ushort4*)(ybf + SY(r, lane * 4)) = o;
        }
    }
    __syncthreads();

    // ---- L2 partial accumulators: live across both phases ----
    f32x4 acc2[4][2];
    #pragma unroll
    for (int m = 0; m < 4; ++m)
        #pragma unroll
        for (int j = 0; j < 2; ++j) acc2[m][j] = (f32x4){0,0,0,0};

    #pragma unroll
    for (int ph = 0; ph < 2; ++ph) {
        // ---- L1 phase: y1 cols [ph*256, ph*256+256); wave n-slice 32 cols ----
        {
            f32x4 acc[4][2];
            #pragma unroll
            for (int m = 0; m < 4; ++m)
                #pragma unroll
                for (int j = 0; j < 2; ++j) acc[m][j] = (f32x4){0,0,0,0};
            const int n0 = ph * 256 + wave * 32;
            const u16* wp0 = W1T + (size_t)(n0 + l16) * 256 + quad * 8;
            const u16* wp1 = W1T + (size_t)(n0 + 16 + l16) * 256 + quad * 8;
            #pragma unroll
            for (int kt = 0; kt < 8; ++kt) {
                const int k0 = kt * 32;
                const bf16x8 bw0 = *(const bf16x8*)(wp0 + k0);
                const bf16x8 bw1 = *(const bf16x8*)(wp1 + k0);
                #pragma unroll
                for (int m = 0; m < 4; ++m) {
                    const bf16x8 af = *(const bf16x8*)(ybf + SY(m * 16 + l16, k0 + quad * 8));
                    acc[m][0] = __builtin_amdgcn_mfma_f32_16x16x32_bf16(af, bw0, acc[m][0], 0, 0, 0);
                    acc[m][1] = __builtin_amdgcn_mfma_f32_16x16x32_bf16(af, bw1, acc[m][1], 0, 0, 0);
                }
            }
            const float bb0 = b1[n0 + l16], bb1 = b1[n0 + 16 + l16];
            __syncthreads();   // yh free (prev phase consumed / first use)
            #pragma unroll
            for (int m = 0; m < 4; ++m)
                #pragma unroll
                for (int r = 0; r < 4; ++r) {
                    const int row = m * 16 + quad * 4 + r;
                    yh[SY(row, wave * 32 + l16)]      = f2b(elu(acc[m][0][r] + bb0));
                    yh[SY(row, wave * 32 + 16 + l16)] = f2b(elu(acc[m][1][r] + bb1));
                }
        }
        __syncthreads();

        // ---- L2 partial: K in [ph*256, ph*256+256); wave n-slice 32 cols ----
        {
            const int n0 = wave * 32;
            const u16* wp0 = W2T + (size_t)(n0 + l16) * 512 + ph * 256 + quad * 8;
            const u16* wp1 = W2T + (size_t)(n0 + 16 + l16) * 512 + ph * 256 + quad * 8;
            #pragma unroll
            for (int kt = 0; kt < 8; ++kt) {
                const int k0 = kt * 32;
                const bf16x8 bw0 = *(const bf16x8*)(wp0 + k0);
                const bf16x8 bw1 = *(const bf16x8*)(wp1 + k0);
                #pragma unroll
                for (int m = 0; m < 4; ++m) {
                    const bf16x8 af = *(const bf16x8*)(yh + SY(m * 16 + l16, k0 + quad * 8));
                    acc2[m][0] = __builtin_amdgcn_mfma_f32_16x16x32_bf16(af, bw0, acc2[m][0], 0, 0, 0);
                    acc2[m][1] = __builtin_amdgcn_mfma_f32_16x16x32_bf16(af, bw1, acc2[m][1], 0, 0, 0);
                }
            }
        }
        __syncthreads();
    }

    // ---- y2 = elu(acc2 + b2) -> ybf (LN data fully consumed) ----
    {
        const float bb0 = b2[wave * 32 + l16], bb1 = b2[wave * 32 + 16 + l16];
        #pragma unroll
        for (int m = 0; m < 4; ++m)
            #pragma unroll
            for (int r = 0; r < 4; ++r) {
                const int row = m * 16 + quad * 4 + r;
                ybf[SY(row, wave * 32 + l16)]      = f2b(elu(acc2[m][0][r] + bb0));
                ybf[SY(row, wave * 32 + 16 + l16)] = f2b(elu(acc2[m][1][r] + bb1));
            }
    }
    __syncthreads();

    // ---- Heads: waves 0..3 -> m-frag = wave; j=0 mean, j=1 logstd ----
    float* lsf = (float*)yh;   // overlay: [64][16] floats (yh free)
    if (wave < 4) {
        f32x4 a0 = {0,0,0,0}, a1 = {0,0,0,0};
        const u16* wp0 = WhT + (size_t)l16 * 256 + quad * 8;          // mean rows 0..15
        const u16* wp1 = WhT + (size_t)(16 + l16) * 256 + quad * 8;   // logstd rows 16..31
        #pragma unroll
        for (int kt = 0; kt < 8; ++kt) {
            const int k0 = kt * 32;
            const bf16x8 af  = *(const bf16x8*)(ybf + SY(wave * 16 + l16, k0 + quad * 8));
            const bf16x8 bw0 = *(const bf16x8*)(wp0 + k0);
            const bf16x8 bw1 = *(const bf16x8*)(wp1 + k0);
            a0 = __builtin_amdgcn_mfma_f32_16x16x32_bf16(af, bw0, a0, 0, 0, 0);
            a1 = __builtin_amdgcn_mfma_f32_16x16x32_bf16(af, bw1, a1, 0, 0, 0);
        }
        if (l16 < 12) {
            const float bbm = bm[l16], bbs = bs[l16];
            #pragma unroll
            for (int r = 0; r < 4; ++r) {
                const int row = wave * 16 + quad * 4 + r;
                out[(size_t)(row0 + row) * 14 + l16] = a0[r] + bbm;
                lsf[row * 16 + l16] = fminf(fmaxf(a1[r] + bbs, -5.0f), 2.0f);
            }
        }
    }
    __syncthreads();
    if (tid < 64) {
        float s = 0.0f;
        #pragma unroll
        for (int q = 0; q < 12; ++q) s += lsf[tid * 16 + q];
        const float LOG2PI = 1.8378770664093453f;
        out[(size_t)(row0 + tid) * 14 + 12] = -s - 6.0f * LOG2PI;
        out[(size_t)(row0 + tid) * 14 + 13] =  s + 6.0f + 6.0f * LOG2PI;
    }
}

// ---------------------------------------------------------------------------
extern "C" void kernel_launch(void* const* d_in, const int* in_sizes, int n_in,
                              void* d_out, int out_size, void* d_ws, size_t ws_size,
                              hipStream_t stream) {
    (void)in_sizes; (void)n_in; (void)out_size; (void)ws_size;
    const float* x    = (const float*)d_in[0];
    const int*   done = (const int*)  d_in[1];
    const float* h0   = (const float*)d_in[2];
    const float* c0   = (const float*)d_in[3];
    const float* W_ih = (const float*)d_in[4];
    const float* W_hh = (const float*)d_in[5];
    const float* b_ih = (const float*)d_in[6];
    const float* b_hh = (const float*)d_in[7];
    const float* lng  = (const float*)d_in[8];
    const float* lnb  = (const float*)d_in[9];
    const float* W1   = (const float*)d_in[10];
    const float* b1   = (const float*)d_in[11];
    const float* W2   = (const float*)d_in[12];
    const float* b2   = (const float*)d_in[13];
    const float* Wm   = (const float*)d_in[14];
    const float* bm   = (const float*)d_in[15];
    const float* Ws   = (const float*)d_in[16];
    const float* bs   = (const float*)d_in[17];
    float* out = (float*)d_out;

    // workspace carve (~52 MB; ws_size >= 135 MB confirmed)
    unsigned char* p = (unsigned char*)d_ws;
    u16* hs    = (u16*)p;              p += (size_t)(T_ + 1) * BH_ * 2;
    u16* xpad  = (u16*)p;              p += (size_t)T_ * B_ * 64 * 2;
    u16* Wcat  = (u16*)p;              p += (size_t)1024 * KP_ * 2;
    u16* W1T   = (u16*)p;              p += (size_t)M1_ * H_ * 2;
    u16* W2T   = (u16*)p;              p += (size_t)M2_ * M1_ * 2;
    u16* WhT   = (u16*)p;              p += (size_t)32 * H_ * 2;

    prep_all<<<4096 + 1824, 256, 0, stream>>>(x, xpad, W_ih, W_hh, W1, W2, Wm, Ws,
                                              Wcat, W1T, W2T, WhT);

    lstm_fuse<<<NBLK_, 1024, 0, stream>>>(
        xpad, done, h0, c0, hs, Wcat, b_ih, b_hh);

    mlp_mfma64<<<(T_ * B_) / 64, 512, 0, stream>>>(
        hs + BH_, out, lng, lnb, W1T, b1, W2T, b2, WhT, bm, bs);
}

// Round 14
// 582.170 us; speedup vs baseline: 2.3885x; 2.1334x over previous
//
#include <hip/hip_runtime.h>
#include <hip/hip_bf16.h>
#include <math.h>

#define T_   64
#define B_   2048
#define OBS_ 48
#define H_   256
#define M1_  512
#define M2_  256
#define A_   12
#define BH_  (B_ * H_)
#define KP_  320   // padded K for scan: 64 (x) + 128 (own h) + 128 (partner h)
#define GROUPS_  128  // row groups (16 rows each)
#define SLICES_  2    // column-slice blocks per group (128 h-cols each)
#define RPB_     16   // rows per block

typedef unsigned short u16;
typedef unsigned long long u64;
typedef __attribute__((ext_vector_type(8))) short bf16x8;
typedef __attribute__((ext_vector_type(4))) float f32x4;

static __device__ __forceinline__ u16 f2b(float f) {
    __hip_bfloat16 h = __float2bfloat16(f);
    return *reinterpret_cast<u16*>(&h);
}
static __device__ __forceinline__ float b2f(u16 u) {
    union { unsigned u32v; float f; } v; v.u32v = ((unsigned)u) << 16; return v.f;
}
static __device__ __forceinline__ float sigm(float x) {
    return 1.0f / (1.0f + __expf(-x));
}
static __device__ __forceinline__ float tanh_fast(float x) {
    x = fminf(fmaxf(x, -15.0f), 15.0f);
    float e = __expf(2.0f * x);
    return (e - 1.0f) / (e + 1.0f);
}
static __device__ __forceinline__ float elu(float x) {
    return x > 0.0f ? x : (__expf(x) - 1.0f);
}

// ---------------------------------------------------------------------------
// Unified pre-pass (one dispatch): blocks 0..4095 = xpad; 4096..5919 = weights.
// Wcat: r7's per-slice K-permutation:
//   k 0..63 = x | 64..191 = own h-half | 192..319 = partner h-half
// row = ((s*8 + w)*4 + g)*16 + jj  <-  src gate-row g*256 + s*128 + w*16 + jj
// ---------------------------------------------------------------------------
__global__ void prep_all(const float* __restrict__ x, u16* __restrict__ xpad,
                         const float* __restrict__ W_ih, const float* __restrict__ W_hh,
                         const float* __restrict__ W1,  const float* __restrict__ W2,
                         const float* __restrict__ Wm,  const float* __restrict__ Ws,
                         u16* __restrict__ Wcat, u16* __restrict__ W1T,
                         u16* __restrict__ W2T,  u16* __restrict__ WhT,
                         unsigned* __restrict__ cnt) {
    const int blk = blockIdx.x, tid = threadIdx.x;
    if (blk < 4096) {
        const int gid = blk * 256 + tid;              // T*B*8 threads exactly
        const int r = gid >> 3, k0 = (gid & 7) * 8;
        u16 tmp[8];
        if (k0 < OBS_) {
            const float4 f0 = *(const float4*)(x + (size_t)r * OBS_ + k0);
            const float4 f1 = *(const float4*)(x + (size_t)r * OBS_ + k0 + 4);
            tmp[0] = f2b(f0.x); tmp[1] = f2b(f0.y); tmp[2] = f2b(f0.z); tmp[3] = f2b(f0.w);
            tmp[4] = f2b(f1.x); tmp[5] = f2b(f1.y); tmp[6] = f2b(f1.z); tmp[7] = f2b(f1.w);
        } else {
            #pragma unroll
            for (int i = 0; i < 8; ++i) tmp[i] = 0;
        }
        *(uint4*)(xpad + (size_t)gid * 8) = *(uint4*)tmp;
        return;
    }
    const int b = blk - 4096;                         // 0..1823
    if (b == 0 && tid < GROUPS_ * SLICES_) cnt[tid] = 0;
    if (b < 1024) {
        const int s = b >> 9, w = (b >> 6) & 7, g = (b >> 4) & 3, jj = b & 15;
        const int src = g * 256 + s * 128 + w * 16 + jj;
        for (int k = tid; k < KP_; k += 256) {
            float v;
            if (k < OBS_)     v = W_ih[src * OBS_ + k];
            else if (k < 64)  v = 0.0f;
            else if (k < 192) v = W_hh[src * H_ + s * 128 + (k - 64)];        // own half
            else              v = W_hh[src * H_ + (1 - s) * 128 + (k - 192)]; // partner half
            Wcat[b * KP_ + k] = f2b(v);
        }
    } else if (b < 1536) {
        const int n = b - 1024;                       // W1T [512][256]
        W1T[n * 256 + tid] = f2b(W1[tid * M1_ + n]);
    } else if (b < 1792) {
        const int n = b - 1536;                       // W2T [256][512]
        W2T[n * 512 + tid]       = f2b(W2[tid * M2_ + n]);
        W2T[n * 512 + tid + 256] = f2b(W2[(tid + 256) * M2_ + n]);
    } else {
        const int n = b - 1792;                       // WhT [32][256]
        float v = 0.0f;
        if (n < 12)                 v = Wm[tid * A_ + n];
        else if (n >= 16 && n < 28) v = Ws[tid * A_ + (n - 16)];
        WhT[n * 256 + tid] = f2b(v);
    }
}

// ---------------------------------------------------------------------------
// Co-resident LSTM scan: round-7 structure VERBATIM (proven 298 us; the
// capacity-optimal topology per r12/r13 spill evidence) + ONE addition:
// SPECULATIVE partner-h prefetch. The 4 KB partner fetch was issued after
// the confirm barrier -> full L3 latency exposed. Now: issue the loads at
// iteration top with the flag prefetch; if the top-read flag was already
// >= t (steady state) the data predates the loads -> valid, land from regs.
// Else DISCARD (speculation may have cached stale lines!) and re-load via
// agent-scope sc1 loads, which bypass the possibly-poisoned local caches.
// Fallback path semantics == r7. Poll/confirm/LDS layout bit-identical.
// ---------------------------------------------------------------------------
#define ASM_(row, chunk) (a_sm + (size_t)(row) * 320 + (size_t)(((chunk) ^ ((row) & 7)) << 3))

__global__ __launch_bounds__(512, 2) void lstm_sync2(
    const u16*  __restrict__ xpad,   // [T][B][64] bf16
    const int*  __restrict__ done,   // [T][B]
    const float* __restrict__ h0,    // [B][256] fp32
    const float* __restrict__ c0,    // [B][256] fp32
    u16*        __restrict__ hs,     // [T+1][B][256] bf16; slices 1..T written
    const u16*  __restrict__ Wcat,   // [1024 permuted][320] bf16, per-slice K-permuted
    const float* __restrict__ b_ih,
    const float* __restrict__ b_hh,
    unsigned*   __restrict__ cnt)    // [256] per-slice step flags (zeroed by prep)
{
    __shared__ u16 a_sm[RPB_ * 320];   // 10 KB
    __shared__ unsigned okf;
    __shared__ unsigned spec_sm;       // 1 = iteration-top flag was ready -> spec valid

    const int tid  = threadIdx.x;
    const int lane = tid & 63;
    const int w    = tid >> 6;               // wave 0..7 -> h-colfrag
    const int quad = lane >> 4, l16 = lane & 15;
    const int grp  = blockIdx.x >> 1;        // 0..127
    const int s    = blockIdx.x & 1;         // 0..1
    const int pidx = blockIdx.x ^ 1;         // partner block (r7 pairing)
    const int b0   = grp * RPB_;
    const int j    = s * 128 + w * 16 + l16; // this lane's h column (0..255)
    const int jrel = w * 16 + l16;           // own-relative column (0..127)
    const int pc0  = (1 - s) * 128;          // partner column base (global)

    // ---- fused biases: 4 gates of column j ----
    float bsum[4];
    #pragma unroll
    for (int g = 0; g < 4; ++g) bsum[g] = b_ih[g * 256 + j] + b_hh[g * 256 + j];

    // ---- persistent c state (pre-masked with done[0]) ----
    float cst[4];
    #pragma unroll
    for (int r = 0; r < 4; ++r) {
        const int row = b0 + quad * 4 + r;
        cst[r] = done[row] ? 0.0f : c0[(size_t)row * H_ + j];
    }

    // ---- this wave's weight slice, register-resident: 4 gates x 10 kt ----
    // ALL accesses use compile-time kt (rule #20).
    bf16x8 Bs[4][10];
    #pragma unroll
    for (int g = 0; g < 4; ++g) {
        const u16* wp = Wcat + (size_t)(((s * 8 + w) * 4 + g) * 16 + l16) * KP_ + quad * 8;
        #pragma unroll
        for (int kt = 0; kt < 10; ++kt)
            Bs[g][kt] = *(const bf16x8*)(wp + kt * 32);
    }

    // ---- pre-loop: stage x(0) and full h0 (masked by done[0], permuted) ----
    if ((tid & 3) == 0) {
        const int idx = tid >> 2, row = idx >> 3, seg = idx & 7;
        *(uint4*)ASM_(row, seg) =
            *(const uint4*)(xpad + (size_t)(b0 + row) * 64 + seg * 8);
    }
    {
        const int row = tid >> 5, c8 = tid & 31;
        const int cglob = c8 * 8;
        const int dn = done[b0 + row];
        const float* hr = h0 + (size_t)(b0 + row) * H_ + cglob;
        u16 tmp[8];
        #pragma unroll
        for (int e = 0; e < 8; ++e) tmp[e] = dn ? (u16)0 : f2b(hr[e]);
        const int chunk = (((cglob >> 7) == s) ? 8 : 24) + ((cglob & 127) >> 3);
        *(uint4*)ASM_(row, chunk) = *(uint4*)tmp;
    }
    __syncthreads();

    // ================= 64-step scan =================
    for (int t = 0; t < T_; ++t) {
        // ---- prefetch partner flag + SPECULATIVE partner-h (4 KB) ----
        unsigned fv = 0;
        if (tid == 0 && t > 0)
            fv = __hip_atomic_load(&cnt[pidx], __ATOMIC_RELAXED,
                                   __HIP_MEMORY_SCOPE_AGENT);
        uint4 hspec; int hrow = 0, hq = 0;
        const bool sth = (t > 0) && (tid < 256);
        if (sth) {
            hrow = tid >> 4; hq = tid & 15;
            hspec = *(const uint4*)(hs + (size_t)t * BH_ +
                                    (size_t)(b0 + hrow) * H_ + pc0 + hq * 8);
        }

        // ---- part A: x + own half, kt 0..5 STATIC = 24 MFMA ----
        f32x4 acc[4];
        #pragma unroll
        for (int g = 0; g < 4; ++g) acc[g] = (f32x4){0, 0, 0, 0};
        #pragma unroll
        for (int kt = 0; kt < 6; ++kt) {
            const bf16x8 af = *(const bf16x8*)ASM_(l16, kt * 4 + quad);
            #pragma unroll
            for (int g = 0; g < 4; ++g)
                acc[g] = __builtin_amdgcn_mfma_f32_16x16x32_bf16(af, Bs[g][kt], acc[g], 0, 0, 0);
        }

        // ---- confirm partner flag (steady state: no spin, one barrier) ----
        if (tid == 0) {
            const unsigned ok0 = (t == 0 || fv >= (unsigned)t) ? 1u : 0u;
            okf = ok0; spec_sm = ok0;
        }
        __syncthreads();
        const unsigned specok = spec_sm;   // block-uniform; read after barrier
        {
            int guard = 0;
            while (!okf) {
                if (tid == 0) {
                    __builtin_amdgcn_s_sleep(1);
                    fv = __hip_atomic_load(&cnt[pidx], __ATOMIC_RELAXED,
                                           __HIP_MEMORY_SCOPE_AGENT);
                    if (fv >= (unsigned)t || ++guard > (1 << 22)) okf = 1u;
                }
                __syncthreads();   // write(okf) -> barrier -> re-read at loop head
            }
        }

        // ---- stage partner-h(t) (chunks 24..39) || x(t+1) ----
        if (sth) {
            const int dn = done[(size_t)t * B_ + b0 + hrow];
            uint4 hv;
            if (specok) {
                hv = hspec;                    // validated: data predates load
            } else {
                // speculation failed: local caches may hold stale lines ->
                // re-read with agent-scope loads (bypass to coherence point)
                const u64* src = (const u64*)(hs + (size_t)t * BH_ +
                                              (size_t)(b0 + hrow) * H_ + pc0 + hq * 8);
                const u64 a = __hip_atomic_load(src,     __ATOMIC_RELAXED,
                                                __HIP_MEMORY_SCOPE_AGENT);
                const u64 bq = __hip_atomic_load(src + 1, __ATOMIC_RELAXED,
                                                 __HIP_MEMORY_SCOPE_AGENT);
                hv = make_uint4((unsigned)a, (unsigned)(a >> 32),
                                (unsigned)bq, (unsigned)(bq >> 32));
            }
            if (dn) hv = make_uint4(0u, 0u, 0u, 0u);
            *(uint4*)ASM_(hrow, 24 + hq) = hv;
        }
        if (t + 1 < T_ && tid >= 256 && tid < 384) {
            const int idx = tid - 256, row = idx >> 3, seg = idx & 7;
            *(uint4*)ASM_(row, seg) =
                *(const uint4*)(xpad + ((size_t)(t + 1) * B_ + b0 + row) * 64 + seg * 8);
        }
        __syncthreads();

        // ---- part B: partner half, kt 6..9 STATIC = 16 MFMA ----
        #pragma unroll
        for (int kt = 6; kt < 10; ++kt) {
            const bf16x8 af = *(const bf16x8*)ASM_(l16, kt * 4 + quad);
            #pragma unroll
            for (int g = 0; g < 4; ++g)
                acc[g] = __builtin_amdgcn_mfma_f32_16x16x32_bf16(af, Bs[g][kt], acc[g], 0, 0, 0);
        }

        // ---- epilogue (no barrier: writes own chunks 8..23, all waves done
        //      reading them in part A before the staging barrier) ----
        u16* hs1 = hs + (size_t)(t + 1) * BH_;
        #pragma unroll
        for (int r = 0; r < 4; ++r) {
            const int rowl = quad * 4 + r;
            const int rowg = b0 + rowl;
            const float gi = acc[0][r] + bsum[0];
            const float gf = acc[1][r] + bsum[1];
            const float gg = acc[2][r] + bsum[2];
            const float go = acc[3][r] + bsum[3];
            const float cn = sigm(gf) * cst[r] + sigm(gi) * tanh_fast(gg);
            const float h  = sigm(go) * tanh_fast(cn);
            const float kp = (t + 1 < T_)
                ? (done[(size_t)(t + 1) * B_ + rowg] ? 0.0f : 1.0f) : 1.0f;
            cst[r] = cn * kp;                      // pre-mask c for step t+1
            const int e = 64 + jrel;               // own half into LDS (chunks 8..23)
            *(ASM_(rowl, e >> 3) + (e & 7)) = f2b(h * kp);
            const unsigned hb = (unsigned)f2b(h);  // unmasked history to global
            const unsigned ob = (unsigned)__shfl_xor((int)hb, 1);
            if ((l16 & 1) == 0) {                  // pack (j, j+1) -> one u32 store
                const unsigned val = hb | (ob << 16);
                __hip_atomic_store((unsigned*)(hs1 + (size_t)rowg * H_ + (j & ~1)), val,
                                   __ATOMIC_RELAXED, __HIP_MEMORY_SCOPE_AGENT);
            }
        }
        __syncthreads();   // drains vmcnt (sc1 stores visible) + LDS order

        // ---- post own flag: h(t+1) published ----
        if (tid == 0 && t + 1 < T_)
            __hip_atomic_store(&cnt[blockIdx.x], (unsigned)(t + 1),
                               __ATOMIC_RELAXED, __HIP_MEMORY_SCOPE_AGENT);
    }
}

// ---------------------------------------------------------------------------
// MLP (round-7 proven, 211 us): 64 rows/block, 512 threads, two-phase y1,
// nontemporal u64 hs loads. (r8 32-row and r10 4-phase variants regressed.)
// ---------------------------------------------------------------------------
#define SY(row, col) ((size_t)(row) * 256 + ((((col) >> 3) ^ ((row) & 7)) << 3) + ((col) & 7))

__global__ __launch_bounds__(512, 4) void mlp_mfma64(
    const u16*  __restrict__ hs,    // [nrows][256] bf16
    float*      __restrict__ out,   // [nrows][14]
    const float* __restrict__ lng, const float* __restrict__ lnb,
    const u16*  __restrict__ W1T, const float* __restrict__ b1,
    const u16*  __restrict__ W2T, const float* __restrict__ b2,
    const u16*  __restrict__ WhT,
    const float* __restrict__ bm, const float* __restrict__ bs)
{
    __shared__ u16 ybf[64 * 256];   // 32 KB swizzled: LN output, later y2
    __shared__ u16 yh [64 * 256];   // 32 KB swizzled: y1 column-half; later ls overlay

    const int tid  = threadIdx.x;
    const int lane = tid & 63;
    const int wave = tid >> 6;        // 0..7
    const int quad = lane >> 4, l16 = lane & 15;
    const int row0 = blockIdx.x * 64;

    // ---- LayerNorm: wave w -> rows w*8..w*8+7; lane holds 4 cols ----
    {
        const float4 gv = *(const float4*)(lng + lane * 4);
        const float4 bv = *(const float4*)(lnb + lane * 4);
        #pragma unroll
        for (int rr = 0; rr < 8; ++rr) {
            const int r = wave * 8 + rr;
            const u64 hv8 = __builtin_nontemporal_load(
                (const u64*)(hs + (size_t)(row0 + r) * H_ + lane * 4));
            const u16 h0v = (u16)(hv8 & 0xffff), h1v = (u16)((hv8 >> 16) & 0xffff);
            const u16 h2v = (u16)((hv8 >> 32) & 0xffff), h3v = (u16)(hv8 >> 48);
            const float v0 = b2f(h0v), v1 = b2f(h1v), v2 = b2f(h2v), v3 = b2f(h3v);
            float s  = v0 + v1 + v2 + v3;
            float ss = v0 * v0 + v1 * v1 + v2 * v2 + v3 * v3;
            #pragma unroll
            for (int off = 32; off > 0; off >>= 1) {
                s  += __shfl_down(s,  off);
                ss += __shfl_down(ss, off);
            }
            s = __shfl(s, 0); ss = __shfl(ss, 0);
            const float mu   = s * (1.0f / 256.0f);
            const float rstd = rsqrtf(ss * (1.0f / 256.0f) - mu * mu + 1e-5f);
            ushort4 o;
            o.x = f2b((v0 - mu) * rstd * gv.x + bv.x);
            o.y = f2b((v1 - mu) * rstd * gv.y + bv.y);
            o.z = f2b((v2 - mu) * rstd * gv.z + bv.z);
            o.w = f2b((v3 - mu) * rstd * gv.w + bv.w);
            *(ushort4*)(ybf + SY(r, lane * 4)) = o;
        }
    }
    __syncthreads();

    // ---- L2 partial accumulators: live across both phases ----
    f32x4 acc2[4][2];
    #pragma unroll
    for (int m = 0; m < 4; ++m)
        #pragma unroll
        for (int j = 0; j < 2; ++j) acc2[m][j] = (f32x4){0,0,0,0};

    #pragma unroll
    for (int ph = 0; ph < 2; ++ph) {
        // ---- L1 phase: y1 cols [ph*256, ph*256+256); wave n-slice 32 cols ----
        {
            f32x4 acc[4][2];
            #pragma unroll
            for (int m = 0; m < 4; ++m)
                #pragma unroll
                for (int j = 0; j < 2; ++j) acc[m][j] = (f32x4){0,0,0,0};
            const int n0 = ph * 256 + wave * 32;
            const u16* wp0 = W1T + (size_t)(n0 + l16) * 256 + quad * 8;
            const u16* wp1 = W1T + (size_t)(n0 + 16 + l16) * 256 + quad * 8;
            #pragma unroll
            for (int kt = 0; kt < 8; ++kt) {
                const int k0 = kt * 32;
                const bf16x8 bw0 = *(const bf16x8*)(wp0 + k0);
                const bf16x8 bw1 = *(const bf16x8*)(wp1 + k0);
                #pragma unroll
                for (int m = 0; m < 4; ++m) {
                    const bf16x8 af = *(const bf16x8*)(ybf + SY(m * 16 + l16, k0 + quad * 8));
                    acc[m][0] = __builtin_amdgcn_mfma_f32_16x16x32_bf16(af, bw0, acc[m][0], 0, 0, 0);
                    acc[m][1] = __builtin_amdgcn_mfma_f32_16x16x32_bf16(af, bw1, acc[m][1], 0, 0, 0);
                }
            }
            const float bb0 = b1[n0 + l16], bb1 = b1[n0 + 16 + l16];
            __syncthreads();   // yh free (prev phase consumed / first use)
            #pragma unroll
            for (int m = 0; m < 4; ++m)
                #pragma unroll
                for (int r = 0; r < 4; ++r) {
                    const int row = m * 16 + quad * 4 + r;
                    yh[SY(row, wave * 32 + l16)]      = f2b(elu(acc[m][0][r] + bb0));
                    yh[SY(row, wave * 32 + 16 + l16)] = f2b(elu(acc[m][1][r] + bb1));
                }
        }
        __syncthreads();

        // ---- L2 partial: K in [ph*256, ph*256+256); wave n-slice 32 cols ----
        {
            const int n0 = wave * 32;
            const u16* wp0 = W2T + (size_t)(n0 + l16) * 512 + ph * 256 + quad * 8;
            const u16* wp1 = W2T + (size_t)(n0 + 16 + l16) * 512 + ph * 256 + quad * 8;
            #pragma unroll
            for (int kt = 0; kt < 8; ++kt) {
                const int k0 = kt * 32;
                const bf16x8 bw0 = *(const bf16x8*)(wp0 + k0);
                const bf16x8 bw1 = *(const bf16x8*)(wp1 + k0);
                #pragma unroll
                for (int m = 0; m < 4; ++m) {
                    const bf16x8 af = *(const bf16x8*)(yh + SY(m * 16 + l16, k0 + quad * 8));
                    acc2[m][0] = __builtin_amdgcn_mfma_f32_16x16x32_bf16(af, bw0, acc2[m][0], 0, 0, 0);
                    acc2[m][1] = __builtin_amdgcn_mfma_f32_16x16x32_bf16(af, bw1, acc2[m][1], 0, 0, 0);
                }
            }
        }
        __syncthreads();
    }

    // ---- y2 = elu(acc2 + b2) -> ybf (LN data fully consumed) ----
    {
        const float bb0 = b2[wave * 32 + l16], bb1 = b2[wave * 32 + 16 + l16];
        #pragma unroll
        for (int m = 0; m < 4; ++m)
            #pragma unroll
            for (int r = 0; r < 4; ++r) {
                const int row = m * 16 + quad * 4 + r;
                ybf[SY(row, wave * 32 + l16)]      = f2b(elu(acc2[m][0][r] + bb0));
                ybf[SY(row, wave * 32 + 16 + l16)] = f2b(elu(acc2[m][1][r] + bb1));
            }
    }
    __syncthreads();

    // ---- Heads: waves 0..3 -> m-frag = wave; j=0 mean, j=1 logstd ----
    float* lsf = (float*)yh;   // overlay: [64][16] floats (yh free)
    if (wave < 4) {
        f32x4 a0 = {0,0,0,0}, a1 = {0,0,0,0};
        const u16* wp0 = WhT + (size_t)l16 * 256 + quad * 8;          // mean rows 0..15
        const u16* wp1 = WhT + (size_t)(16 + l16) * 256 + quad * 8;   // logstd rows 16..31
        #pragma unroll
        for (int kt = 0; kt < 8; ++kt) {
            const int k0 = kt * 32;
            const bf16x8 af  = *(const bf16x8*)(ybf + SY(wave * 16 + l16, k0 + quad * 8));
            const bf16x8 bw0 = *(const bf16x8*)(wp0 + k0);
            const bf16x8 bw1 = *(const bf16x8*)(wp1 + k0);
            a0 = __builtin_amdgcn_mfma_f32_16x16x32_bf16(af, bw0, a0, 0, 0, 0);
            a1 = __builtin_amdgcn_mfma_f32_16x16x32_bf16(af, bw1, a1, 0, 0, 0);
        }
        if (l16 < 12) {
            const float bbm = bm[l16], bbs = bs[l16];
            #pragma unroll
            for (int r = 0; r < 4; ++r) {
                const int row = wave * 16 + quad * 4 + r;
                out[(size_t)(row0 + row) * 14 + l16] = a0[r] + bbm;
                lsf[row * 16 + l16] = fminf(fmaxf(a1[r] + bbs, -5.0f), 2.0f);
            }
        }
    }
    __syncthreads();
    if (tid < 64) {
        float s = 0.0f;
        #pragma unroll
        for (int q = 0; q < 12; ++q) s += lsf[tid * 16 + q];
        const float LOG2PI = 1.8378770664093453f;
        out[(size_t)(row0 + tid) * 14 + 12] = -s - 6.0f * LOG2PI;
        out[(size_t)(row0 + tid) * 14 + 13] =  s + 6.0f + 6.0f * LOG2PI;
    }
}

// ---------------------------------------------------------------------------
extern "C" void kernel_launch(void* const* d_in, const int* in_sizes, int n_in,
                              void* d_out, int out_size, void* d_ws, size_t ws_size,
                              hipStream_t stream) {
    (void)in_sizes; (void)n_in; (void)out_size; (void)ws_size;
    const float* x    = (const float*)d_in[0];
    const int*   done = (const int*)  d_in[1];
    const float* h0   = (const float*)d_in[2];
    const float* c0   = (const float*)d_in[3];
    const float* W_ih = (const float*)d_in[4];
    const float* W_hh = (const float*)d_in[5];
    const float* b_ih = (const float*)d_in[6];
    const float* b_hh = (const float*)d_in[7];
    const float* lng  = (const float*)d_in[8];
    const float* lnb  = (const float*)d_in[9];
    const float* W1   = (const float*)d_in[10];
    const float* b1   = (const float*)d_in[11];
    const float* W2   = (const float*)d_in[12];
    const float* b2   = (const float*)d_in[13];
    const float* Wm   = (const float*)d_in[14];
    const float* bm   = (const float*)d_in[15];
    const float* Ws   = (const float*)d_in[16];
    const float* bs   = (const float*)d_in[17];
    float* out = (float*)d_out;

    // workspace carve (~52 MB; ws_size >= 135 MB confirmed)
    unsigned char* p = (unsigned char*)d_ws;
    u16* hs    = (u16*)p;              p += (size_t)(T_ + 1) * BH_ * 2;
    u16* xpad  = (u16*)p;              p += (size_t)T_ * B_ * 64 * 2;
    u16* Wcat  = (u16*)p;              p += (size_t)1024 * KP_ * 2;
    u16* W1T   = (u16*)p;              p += (size_t)M1_ * H_ * 2;
    u16* W2T   = (u16*)p;              p += (size_t)M2_ * M1_ * 2;
    u16* WhT   = (u16*)p;              p += (size_t)32 * H_ * 2;
    unsigned* cnt = (unsigned*)p;      p += 1024;

    prep_all<<<4096 + 1824, 256, 0, stream>>>(x, xpad, W_ih, W_hh, W1, W2, Wm, Ws,
                                              Wcat, W1T, W2T, WhT, cnt);

    lstm_sync2<<<GROUPS_ * SLICES_, 512, 0, stream>>>(
        xpad, done, h0, c0, hs, Wcat, b_ih, b_hh, cnt);

    mlp_mfma64<<<(T_ * B_) / 64, 512, 0, stream>>>(
        hs + BH_, out, lng, lnb, W1T, b1, W2T, b2, WhT, bm, bs);
}

// Round 15
// 577.034 us; speedup vs baseline: 2.4097x; 1.0089x over previous
//
#include <hip/hip_runtime.h>
#include <hip/hip_bf16.h>
#include <math.h>

#define T_   64
#define B_   2048
#define OBS_ 48
#define H_   256
#define M1_  512
#define M2_  256
#define A_   12
#define BH_  (B_ * H_)
#define KP_  320   // padded K for scan: 64 (x) + 128 (own h) + 128 (partner h)
#define GROUPS_  128  // row groups (16 rows each)
#define SLICES_  2    // column-slice blocks per group (128 h-cols each)
#define RPB_     16   // rows per block
#define NSCAN_   (GROUPS_ * SLICES_)   // 256 scan blocks (grid head)
#define NMLP_    ((T_ * B_) / 64)      // 2048 MLP blocks (grid tail)

typedef unsigned short u16;
typedef unsigned long long u64;
typedef __attribute__((ext_vector_type(8))) short bf16x8;
typedef __attribute__((ext_vector_type(4))) float f32x4;

static __device__ __forceinline__ u16 f2b(float f) {
    __hip_bfloat16 h = __float2bfloat16(f);
    return *reinterpret_cast<u16*>(&h);
}
static __device__ __forceinline__ float b2f(u16 u) {
    union { unsigned u32v; float f; } v; v.u32v = ((unsigned)u) << 16; return v.f;
}
static __device__ __forceinline__ float sigm(float x) {
    return 1.0f / (1.0f + __expf(-x));
}
static __device__ __forceinline__ float tanh_fast(float x) {
    x = fminf(fmaxf(x, -15.0f), 15.0f);
    float e = __expf(2.0f * x);
    return (e - 1.0f) / (e + 1.0f);
}
static __device__ __forceinline__ float elu(float x) {
    return x > 0.0f ? x : (__expf(x) - 1.0f);
}

// ---------------------------------------------------------------------------
// Unified pre-pass (one dispatch): blocks 0..4095 = xpad; 4096..5919 = weights.
// Wcat: r7's per-slice K-permutation:
//   k 0..63 = x | 64..191 = own h-half | 192..319 = partner h-half
// row = ((s*8 + w)*4 + g)*16 + jj  <-  src gate-row g*256 + s*128 + w*16 + jj
// ---------------------------------------------------------------------------
__global__ void prep_all(const float* __restrict__ x, u16* __restrict__ xpad,
                         const float* __restrict__ W_ih, const float* __restrict__ W_hh,
                         const float* __restrict__ W1,  const float* __restrict__ W2,
                         const float* __restrict__ Wm,  const float* __restrict__ Ws,
                         u16* __restrict__ Wcat, u16* __restrict__ W1T,
                         u16* __restrict__ W2T,  u16* __restrict__ WhT,
                         unsigned* __restrict__ cnt) {
    const int blk = blockIdx.x, tid = threadIdx.x;
    if (blk < 4096) {
        const int gid = blk * 256 + tid;              // T*B*8 threads exactly
        const int r = gid >> 3, k0 = (gid & 7) * 8;
        u16 tmp[8];
        if (k0 < OBS_) {
            const float4 f0 = *(const float4*)(x + (size_t)r * OBS_ + k0);
            const float4 f1 = *(const float4*)(x + (size_t)r * OBS_ + k0 + 4);
            tmp[0] = f2b(f0.x); tmp[1] = f2b(f0.y); tmp[2] = f2b(f0.z); tmp[3] = f2b(f0.w);
            tmp[4] = f2b(f1.x); tmp[5] = f2b(f1.y); tmp[6] = f2b(f1.z); tmp[7] = f2b(f1.w);
        } else {
            #pragma unroll
            for (int i = 0; i < 8; ++i) tmp[i] = 0;
        }
        *(uint4*)(xpad + (size_t)gid * 8) = *(uint4*)tmp;
        return;
    }
    const int b = blk - 4096;                         // 0..1823
    if (b == 0 && tid < NSCAN_) cnt[tid] = 0;
    if (b < 1024) {
        const int s = b >> 9, w = (b >> 6) & 7, g = (b >> 4) & 3, jj = b & 15;
        const int src = g * 256 + s * 128 + w * 16 + jj;
        for (int k = tid; k < KP_; k += 256) {
            float v;
            if (k < OBS_)     v = W_ih[src * OBS_ + k];
            else if (k < 64)  v = 0.0f;
            else if (k < 192) v = W_hh[src * H_ + s * 128 + (k - 64)];        // own half
            else              v = W_hh[src * H_ + (1 - s) * 128 + (k - 192)]; // partner half
            Wcat[b * KP_ + k] = f2b(v);
        }
    } else if (b < 1536) {
        const int n = b - 1024;                       // W1T [512][256]
        W1T[n * 256 + tid] = f2b(W1[tid * M1_ + n]);
    } else if (b < 1792) {
        const int n = b - 1536;                       // W2T [256][512]
        W2T[n * 512 + tid]       = f2b(W2[tid * M2_ + n]);
        W2T[n * 512 + tid + 256] = f2b(W2[(tid + 256) * M2_ + n]);
    } else {
        const int n = b - 1792;                       // WhT [32][256]
        float v = 0.0f;
        if (n < 12)                 v = Wm[tid * A_ + n];
        else if (n >= 16 && n < 28) v = Ws[tid * A_ + (n - 16)];
        WhT[n * 256 + tid] = f2b(v);
    }
}

// ---------------------------------------------------------------------------
// FUSED scan + MLP mega-kernel (round 15).
// Blocks 0..255 = r7 scan role (proven 298 us; only change: the step flag is
// posted after EVERY step, so MLP consumers can see the final slice).
// Blocks 256..2303 = r7 MLP role (proven 211 us), each first polling the 8
// group/slice flags covering its 64 rows (cnt >= ts, agent scope) - the
// exact store->drain->flag visibility protocol proven for the pair exchange.
// Resource fit per CU during overlap: scan (8 waves, 64 KB) + 1 MLP block
// (8 waves, 64 KB) = 16/32 waves, 128/160 KB LDS. Scan blocks head the
// grid -> dispatched first; the MLP poll guard turns any dispatch-order
// pathology into a wrong answer (~50 ms), never a hang.
// ---------------------------------------------------------------------------
#define ASM_(row, chunk) (a_sm + (size_t)(row) * 320 + (size_t)(((chunk) ^ ((row) & 7)) << 3))
#define SY(row, col) ((size_t)(row) * 256 + ((((col) >> 3) ^ ((row) & 7)) << 3) + ((col) & 7))

__global__ __launch_bounds__(512, 2) void scan_mlp(
    const u16*  __restrict__ xpad,   // [T][B][64] bf16
    const int*  __restrict__ done,   // [T][B]
    const float* __restrict__ h0,    // [B][256] fp32
    const float* __restrict__ c0,    // [B][256] fp32
    u16*        __restrict__ hs,     // [T+1][B][256] bf16; slices 1..T written
    const u16*  __restrict__ Wcat,   // [1024 permuted][320] bf16
    const float* __restrict__ b_ih,
    const float* __restrict__ b_hh,
    unsigned*   __restrict__ cnt,    // [256] per-slice step flags (zeroed by prep)
    float*      __restrict__ out,    // [T*B][14]
    const float* __restrict__ lng, const float* __restrict__ lnb,
    const u16*  __restrict__ W1T, const float* __restrict__ b1,
    const u16*  __restrict__ W2T, const float* __restrict__ b2,
    const u16*  __restrict__ WhT,
    const float* __restrict__ bm, const float* __restrict__ bs)
{
    __shared__ u16 smem[32768];      // 64 KB: scan uses 10 KB; MLP uses all
    __shared__ unsigned okf;

    const int tid  = threadIdx.x;
    const int lane = tid & 63;
    const int quad = (lane >> 4), l16 = lane & 15;

    if (blockIdx.x < NSCAN_) {
        // ================= SCAN ROLE (r7 verbatim) =================
        u16* a_sm = smem;
        const int w    = tid >> 6;               // wave 0..7 -> h-colfrag
        const int grp  = blockIdx.x >> 1;        // 0..127
        const int s    = blockIdx.x & 1;         // 0..1
        const int pidx = blockIdx.x ^ 1;         // partner block
        const int b0   = grp * RPB_;
        const int j    = s * 128 + w * 16 + l16; // this lane's h column
        const int jrel = w * 16 + l16;           // own-relative column
        const int pc0  = (1 - s) * 128;          // partner column base

        float bsum[4];
        #pragma unroll
        for (int g = 0; g < 4; ++g) bsum[g] = b_ih[g * 256 + j] + b_hh[g * 256 + j];

        float cst[4];
        #pragma unroll
        for (int r = 0; r < 4; ++r) {
            const int row = b0 + quad * 4 + r;
            cst[r] = done[row] ? 0.0f : c0[(size_t)row * H_ + j];
        }

        // weight slice, register-resident: 4 gates x 10 kt (all static idx)
        bf16x8 Bs[4][10];
        #pragma unroll
        for (int g = 0; g < 4; ++g) {
            const u16* wp = Wcat + (size_t)(((s * 8 + w) * 4 + g) * 16 + l16) * KP_ + quad * 8;
            #pragma unroll
            for (int kt = 0; kt < 10; ++kt)
                Bs[g][kt] = *(const bf16x8*)(wp + kt * 32);
        }

        // pre-loop staging: x(0) + full h0 (masked, permuted)
        if ((tid & 3) == 0) {
            const int idx = tid >> 2, row = idx >> 3, seg = idx & 7;
            *(uint4*)ASM_(row, seg) =
                *(const uint4*)(xpad + (size_t)(b0 + row) * 64 + seg * 8);
        }
        {
            const int row = tid >> 5, c8 = tid & 31;
            const int cglob = c8 * 8;
            const int dn = done[b0 + row];
            const float* hr = h0 + (size_t)(b0 + row) * H_ + cglob;
            u16 tmp[8];
            #pragma unroll
            for (int e = 0; e < 8; ++e) tmp[e] = dn ? (u16)0 : f2b(hr[e]);
            const int chunk = (((cglob >> 7) == s) ? 8 : 24) + ((cglob & 127) >> 3);
            *(uint4*)ASM_(row, chunk) = *(uint4*)tmp;
        }
        __syncthreads();

        for (int t = 0; t < T_; ++t) {
            // prefetch partner flag (consumed after part A)
            unsigned fv = 0;
            if (tid == 0 && t > 0)
                fv = __hip_atomic_load(&cnt[pidx], __ATOMIC_RELAXED,
                                       __HIP_MEMORY_SCOPE_AGENT);

            // part A: x + own half, kt 0..5 = 24 MFMA
            f32x4 acc[4];
            #pragma unroll
            for (int g = 0; g < 4; ++g) acc[g] = (f32x4){0, 0, 0, 0};
            #pragma unroll
            for (int kt = 0; kt < 6; ++kt) {
                const bf16x8 af = *(const bf16x8*)ASM_(l16, kt * 4 + quad);
                #pragma unroll
                for (int g = 0; g < 4; ++g)
                    acc[g] = __builtin_amdgcn_mfma_f32_16x16x32_bf16(af, Bs[g][kt], acc[g], 0, 0, 0);
            }

            // confirm partner flag (steady state: no spin, one barrier)
            if (tid == 0) okf = (t == 0 || fv >= (unsigned)t) ? 1u : 0u;
            __syncthreads();
            {
                int guard = 0;
                while (!okf) {
                    if (tid == 0) {
                        __builtin_amdgcn_s_sleep(1);
                        fv = __hip_atomic_load(&cnt[pidx], __ATOMIC_RELAXED,
                                               __HIP_MEMORY_SCOPE_AGENT);
                        if (fv >= (unsigned)t || ++guard > (1 << 22)) okf = 1u;
                    }
                    __syncthreads();
                }
            }

            // stage partner-h(t) (thr 0..255, chunks 24..39) || x(t+1)
            if (t > 0 && tid < 256) {
                const u16* hst = hs + (size_t)t * BH_;
                const int row = tid >> 4, q = tid & 15;
                const int dn = done[(size_t)t * B_ + b0 + row];
                uint4 hv = *(const uint4*)(hst + (size_t)(b0 + row) * H_ + pc0 + q * 8);
                if (dn) hv = make_uint4(0u, 0u, 0u, 0u);
                *(uint4*)ASM_(row, 24 + q) = hv;
            }
            if (t + 1 < T_ && tid >= 256 && tid < 384) {
                const int idx = tid - 256, row = idx >> 3, seg = idx & 7;
                *(uint4*)ASM_(row, seg) =
                    *(const uint4*)(xpad + ((size_t)(t + 1) * B_ + b0 + row) * 64 + seg * 8);
            }
            __syncthreads();

            // part B: partner half, kt 6..9 = 16 MFMA
            #pragma unroll
            for (int kt = 6; kt < 10; ++kt) {
                const bf16x8 af = *(const bf16x8*)ASM_(l16, kt * 4 + quad);
                #pragma unroll
                for (int g = 0; g < 4; ++g)
                    acc[g] = __builtin_amdgcn_mfma_f32_16x16x32_bf16(af, Bs[g][kt], acc[g], 0, 0, 0);
            }

            // epilogue (no barrier: writes own chunks 8..23 only)
            u16* hs1 = hs + (size_t)(t + 1) * BH_;
            #pragma unroll
            for (int r = 0; r < 4; ++r) {
                const int rowl = quad * 4 + r;
                const int rowg = b0 + rowl;
                const float gi = acc[0][r] + bsum[0];
                const float gf = acc[1][r] + bsum[1];
                const float gg = acc[2][r] + bsum[2];
                const float go = acc[3][r] + bsum[3];
                const float cn = sigm(gf) * cst[r] + sigm(gi) * tanh_fast(gg);
                const float h  = sigm(go) * tanh_fast(cn);
                const float kp = (t + 1 < T_)
                    ? (done[(size_t)(t + 1) * B_ + rowg] ? 0.0f : 1.0f) : 1.0f;
                cst[r] = cn * kp;                      // pre-mask c for step t+1
                const int e = 64 + jrel;               // own half into LDS
                *(ASM_(rowl, e >> 3) + (e & 7)) = f2b(h * kp);
                const unsigned hb = (unsigned)f2b(h);  // unmasked history
                const unsigned ob = (unsigned)__shfl_xor((int)hb, 1);
                if ((l16 & 1) == 0) {                  // pack (j, j+1) -> u32
                    const unsigned val = hb | (ob << 16);
                    __hip_atomic_store((unsigned*)(hs1 + (size_t)rowg * H_ + (j & ~1)), val,
                                       __ATOMIC_RELAXED, __HIP_MEMORY_SCOPE_AGENT);
                }
            }
            __syncthreads();   // drains vmcnt (sc1 stores visible) + LDS order

            // post flag EVERY step (incl. last) - MLP consumers need it
            if (tid == 0)
                __hip_atomic_store(&cnt[blockIdx.x], (unsigned)(t + 1),
                                   __ATOMIC_RELAXED, __HIP_MEMORY_SCOPE_AGENT);
        }
        return;
    }

    // ================= MLP ROLE (r7 verbatim + entry poll) =================
    u16* ybf = smem;                 // 32 KB
    u16* yh  = smem + 16384;         // 32 KB
    const int wave = tid >> 6;       // 0..7
    const int mbid = blockIdx.x - NSCAN_;
    const int row0 = mbid * 64;      // global row in [0, T*B)
    const u16* hsr = hs + BH_;       // slice-1-based view (as before)

    // ---- wait until hs slice (1 + row0/B_) rows [row0%B, +64) are published ----
    {
        const int ts = row0 / B_ + 1;            // required cnt value
        const int g0 = (row0 % B_) / RPB_;       // 4 consecutive groups
        if (tid < 8) {
            const int grp = g0 + (tid >> 1), s = tid & 1;
            int guard = 0;
            while (__hip_atomic_load(&cnt[grp * 2 + s], __ATOMIC_RELAXED,
                                     __HIP_MEMORY_SCOPE_AGENT) < (unsigned)ts) {
                __builtin_amdgcn_s_sleep(2);
                if (++guard > (1 << 20)) break;  // pathology -> wrong answer, not hang
            }
        }
        __syncthreads();
    }

    // ---- LayerNorm: wave w -> rows w*8..w*8+7; lane holds 4 cols ----
    {
        const float4 gv = *(const float4*)(lng + lane * 4);
        const float4 bv = *(const float4*)(lnb + lane * 4);
        #pragma unroll
        for (int rr = 0; rr < 8; ++rr) {
            const int r = wave * 8 + rr;
            const u64 hv8 = __builtin_nontemporal_load(
                (const u64*)(hsr + (size_t)(row0 + r) * H_ + lane * 4));
            const u16 h0v = (u16)(hv8 & 0xffff), h1v = (u16)((hv8 >> 16) & 0xffff);
            const u16 h2v = (u16)((hv8 >> 32) & 0xffff), h3v = (u16)(hv8 >> 48);
            const float v0 = b2f(h0v), v1 = b2f(h1v), v2 = b2f(h2v), v3 = b2f(h3v);
            float s  = v0 + v1 + v2 + v3;
            float ss = v0 * v0 + v1 * v1 + v2 * v2 + v3 * v3;
            #pragma unroll
            for (int off = 32; off > 0; off >>= 1) {
                s  += __shfl_down(s,  off);
                ss += __shfl_down(ss, off);
            }
            s = __shfl(s, 0); ss = __shfl(ss, 0);
            const float mu   = s * (1.0f / 256.0f);
            const float rstd = rsqrtf(ss * (1.0f / 256.0f) - mu * mu + 1e-5f);
            ushort4 o;
            o.x = f2b((v0 - mu) * rstd * gv.x + bv.x);
            o.y = f2b((v1 - mu) * rstd * gv.y + bv.y);
            o.z = f2b((v2 - mu) * rstd * gv.z + bv.z);
            o.w = f2b((v3 - mu) * rstd * gv.w + bv.w);
            *(ushort4*)(ybf + SY(r, lane * 4)) = o;
        }
    }
    __syncthreads();

    // ---- L2 partial accumulators across both phases ----
    f32x4 acc2[4][2];
    #pragma unroll
    for (int m = 0; m < 4; ++m)
        #pragma unroll
        for (int jj = 0; jj < 2; ++jj) acc2[m][jj] = (f32x4){0,0,0,0};

    #pragma unroll
    for (int ph = 0; ph < 2; ++ph) {
        {
            f32x4 acc[4][2];
            #pragma unroll
            for (int m = 0; m < 4; ++m)
                #pragma unroll
                for (int jj = 0; jj < 2; ++jj) acc[m][jj] = (f32x4){0,0,0,0};
            const int n0 = ph * 256 + wave * 32;
            const u16* wp0 = W1T + (size_t)(n0 + l16) * 256 + quad * 8;
            const u16* wp1 = W1T + (size_t)(n0 + 16 + l16) * 256 + quad * 8;
            #pragma unroll
            for (int kt = 0; kt < 8; ++kt) {
                const int k0 = kt * 32;
                const bf16x8 bw0 = *(const bf16x8*)(wp0 + k0);
                const bf16x8 bw1 = *(const bf16x8*)(wp1 + k0);
                #pragma unroll
                for (int m = 0; m < 4; ++m) {
                    const bf16x8 af = *(const bf16x8*)(ybf + SY(m * 16 + l16, k0 + quad * 8));
                    acc[m][0] = __builtin_amdgcn_mfma_f32_16x16x32_bf16(af, bw0, acc[m][0], 0, 0, 0);
                    acc[m][1] = __builtin_amdgcn_mfma_f32_16x16x32_bf16(af, bw1, acc[m][1], 0, 0, 0);
                }
            }
            const float bb0 = b1[n0 + l16], bb1 = b1[n0 + 16 + l16];
            __syncthreads();   // yh free
            #pragma unroll
            for (int m = 0; m < 4; ++m)
                #pragma unroll
                for (int r = 0; r < 4; ++r) {
                    const int row = m * 16 + quad * 4 + r;
                    yh[SY(row, wave * 32 + l16)]      = f2b(elu(acc[m][0][r] + bb0));
                    yh[SY(row, wave * 32 + 16 + l16)] = f2b(elu(acc[m][1][r] + bb1));
                }
        }
        __syncthreads();

        {
            const int n0 = wave * 32;
            const u16* wp0 = W2T + (size_t)(n0 + l16) * 512 + ph * 256 + quad * 8;
            const u16* wp1 = W2T + (size_t)(n0 + 16 + l16) * 512 + ph * 256 + quad * 8;
            #pragma unroll
            for (int kt = 0; kt < 8; ++kt) {
                const int k0 = kt * 32;
                const bf16x8 bw0 = *(const bf16x8*)(wp0 + k0);
                const bf16x8 bw1 = *(const bf16x8*)(wp1 + k0);
                #pragma unroll
                for (int m = 0; m < 4; ++m) {
                    const bf16x8 af = *(const bf16x8*)(yh + SY(m * 16 + l16, k0 + quad * 8));
                    acc2[m][0] = __builtin_amdgcn_mfma_f32_16x16x32_bf16(af, bw0, acc2[m][0], 0, 0, 0);
                    acc2[m][1] = __builtin_amdgcn_mfma_f32_16x16x32_bf16(af, bw1, acc2[m][1], 0, 0, 0);
                }
            }
        }
        __syncthreads();
    }

    // ---- y2 = elu(acc2 + b2) -> ybf ----
    {
        const float bb0 = b2[wave * 32 + l16], bb1 = b2[wave * 32 + 16 + l16];
        #pragma unroll
        for (int m = 0; m < 4; ++m)
            #pragma unroll
            for (int r = 0; r < 4; ++r) {
                const int row = m * 16 + quad * 4 + r;
                ybf[SY(row, wave * 32 + l16)]      = f2b(elu(acc2[m][0][r] + bb0));
                ybf[SY(row, wave * 32 + 16 + l16)] = f2b(elu(acc2[m][1][r] + bb1));
            }
    }
    __syncthreads();

    // ---- Heads ----
    float* lsf = (float*)yh;   // overlay: [64][16] floats
    if (wave < 4) {
        f32x4 a0 = {0,0,0,0}, a1 = {0,0,0,0};
        const u16* wp0 = WhT + (size_t)l16 * 256 + quad * 8;          // mean
        const u16* wp1 = WhT + (size_t)(16 + l16) * 256 + quad * 8;   // logstd
        #pragma unroll
        for (int kt = 0; kt < 8; ++kt) {
            const int k0 = kt * 32;
            const bf16x8 af  = *(const bf16x8*)(ybf + SY(wave * 16 + l16, k0 + quad * 8));
            const bf16x8 bw0 = *(const bf16x8*)(wp0 + k0);
            const bf16x8 bw1 = *(const bf16x8*)(wp1 + k0);
            a0 = __builtin_amdgcn_mfma_f32_16x16x32_bf16(af, bw0, a0, 0, 0, 0);
            a1 = __builtin_amdgcn_mfma_f32_16x16x32_bf16(af, bw1, a1, 0, 0, 0);
        }
        if (l16 < 12) {
            const float bbm = bm[l16], bbs = bs[l16];
            #pragma unroll
            for (int r = 0; r < 4; ++r) {
                const int row = wave * 16 + quad * 4 + r;
                out[(size_t)(row0 + row) * 14 + l16] = a0[r] + bbm;
                lsf[row * 16 + l16] = fminf(fmaxf(a1[r] + bbs, -5.0f), 2.0f);
            }
        }
    }
    __syncthreads();
    if (tid < 64) {
        float s = 0.0f;
        #pragma unroll
        for (int q = 0; q < 12; ++q) s += lsf[tid * 16 + q];
        const float LOG2PI = 1.8378770664093453f;
        out[(size_t)(row0 + tid) * 14 + 12] = -s - 6.0f * LOG2PI;
        out[(size_t)(row0 + tid) * 14 + 13] =  s + 6.0f + 6.0f * LOG2PI;
    }
}

// ---------------------------------------------------------------------------
extern "C" void kernel_launch(void* const* d_in, const int* in_sizes, int n_in,
                              void* d_out, int out_size, void* d_ws, size_t ws_size,
                              hipStream_t stream) {
    (void)in_sizes; (void)n_in; (void)out_size; (void)ws_size;
    const float* x    = (const float*)d_in[0];
    const int*   done = (const int*)  d_in[1];
    const float* h0   = (const float*)d_in[2];
    const float* c0   = (const float*)d_in[3];
    const float* W_ih = (const float*)d_in[4];
    const float* W_hh = (const float*)d_in[5];
    const float* b_ih = (const float*)d_in[6];
    const float* b_hh = (const float*)d_in[7];
    const float* lng  = (const float*)d_in[8];
    const float* lnb  = (const float*)d_in[9];
    const float* W1   = (const float*)d_in[10];
    const float* b1   = (const float*)d_in[11];
    const float* W2   = (const float*)d_in[12];
    const float* b2   = (const float*)d_in[13];
    const float* Wm   = (const float*)d_in[14];
    const float* bm   = (const float*)d_in[15];
    const float* Ws   = (const float*)d_in[16];
    const float* bs   = (const float*)d_in[17];
    float* out = (float*)d_out;

    // workspace carve (~52 MB; ws_size >= 135 MB confirmed)
    unsigned char* p = (unsigned char*)d_ws;
    u16* hs    = (u16*)p;              p += (size_t)(T_ + 1) * BH_ * 2;
    u16* xpad  = (u16*)p;              p += (size_t)T_ * B_ * 64 * 2;
    u16* Wcat  = (u16*)p;              p += (size_t)1024 * KP_ * 2;
    u16* W1T   = (u16*)p;              p += (size_t)M1_ * H_ * 2;
    u16* W2T   = (u16*)p;              p += (size_t)M2_ * M1_ * 2;
    u16* WhT   = (u16*)p;              p += (size_t)32 * H_ * 2;
    unsigned* cnt = (unsigned*)p;      p += 1024;

    prep_all<<<4096 + 1824, 256, 0, stream>>>(x, xpad, W_ih, W_hh, W1, W2, Wm, Ws,
                                              Wcat, W1T, W2T, WhT, cnt);

    scan_mlp<<<NSCAN_ + NMLP_, 512, 0, stream>>>(
        xpad, done, h0, c0, hs, Wcat, b_ih, b_hh, cnt,
        out, lng, lnb, W1T, b1, W2T, b2, WhT, bm, bs);
}